// Round 1
// baseline (199.664 us; speedup 1.0000x reference)
//
#include <hip/hip_runtime.h>

// ---------------------------------------------------------------------------
// DeltaModel: B=256, L=2048, H=V=64.
// Key identities:
//  (1) hs/k/v/q depend only on token id (V=64)  -> 64x64 tables.
//  (2) r = M_N q with M linear recurrence       -> backward vector scan:
//      u=q; for t=N..1: s=k_t.u; r+=s*v_t; u-=s*k_t.   (k_t unit norm)
// ---------------------------------------------------------------------------

#define DPP_ADD_F32(x, ctrl, rm, bm, bc)                                      \
  (x) = (x) + __int_as_float(__builtin_amdgcn_update_dpp(                     \
            0, __float_as_int(x), (ctrl), (rm), (bm), (bc)))

// Full 64-lane sum; result returned uniform (via SGPR readlane of lane 63).
__device__ __forceinline__ float wave_sum64(float x) {
  DPP_ADD_F32(x, 0x111, 0xf, 0xf, true);   // row_shr:1
  DPP_ADD_F32(x, 0x112, 0xf, 0xf, true);   // row_shr:2
  DPP_ADD_F32(x, 0x114, 0xf, 0xf, true);   // row_shr:4
  DPP_ADD_F32(x, 0x118, 0xf, 0xf, true);   // row_shr:8  -> lane 15 of each row16 has row sum
  DPP_ADD_F32(x, 0x142, 0xa, 0xf, false);  // row_bcast:15 into rows 1,3
  DPP_ADD_F32(x, 0x143, 0xc, 0xf, false);  // row_bcast:31 into rows 2,3 -> lane 63 = total
  return __int_as_float(__builtin_amdgcn_readlane(__float_as_int(x), 63));
}

// ---------------------------------------------------------------------------
// Kernel A: build per-token tables k_n, v, q  (64 tokens, one block each).
// ---------------------------------------------------------------------------
__global__ __launch_bounds__(64) void build_tables(
    const float* __restrict__ embed, const float* __restrict__ W1,
    const float* __restrict__ b1, const float* __restrict__ W2,
    const float* __restrict__ b2, const float* __restrict__ gamma,
    const float* __restrict__ beta, const float* __restrict__ Wk,
    const float* __restrict__ Wv, const float* __restrict__ Wq,
    float* __restrict__ k_tab, float* __restrict__ v_tab,
    float* __restrict__ q_tab) {
  __shared__ float e_s[64];
  __shared__ float f1_s[128];
  __shared__ float hs_s[64];
  const int tok = blockIdx.x;
  const int l = threadIdx.x;

  const float e = embed[tok * 64 + l];
  e_s[l] = e;
  __syncthreads();

  // FF layer 1: out[j] = relu(b1[j] + e . W1[j,:])  (thread does j=l and j=l+64)
  float a0 = b1[l], a1 = b1[l + 64];
#pragma unroll
  for (int h = 0; h < 64; ++h) {
    const float eh = e_s[h];
    a0 = fmaf(eh, W1[l * 64 + h], a0);
    a1 = fmaf(eh, W1[(l + 64) * 64 + h], a1);
  }
  f1_s[l] = fmaxf(a0, 0.f);
  f1_s[l + 64] = fmaxf(a1, 0.f);
  __syncthreads();

  // FF layer 2 + residual
  float acc = b2[l];
#pragma unroll
  for (int j = 0; j < 128; ++j) acc = fmaf(f1_s[j], W2[l * 128 + j], acc);
  const float hval = e + acc;

  // LayerNorm (biased var, eps=1e-5)
  const float mu = wave_sum64(hval) * (1.f / 64.f);
  const float d = hval - mu;
  const float var = wave_sum64(d * d) * (1.f / 64.f);
  const float hs = d * (1.f / sqrtf(var + 1e-5f)) * gamma[l] + beta[l];
  hs_s[l] = hs;
  __syncthreads();

  // k, v, q projections
  float kk = 0.f, vv = 0.f, qq = 0.f;
#pragma unroll
  for (int h = 0; h < 64; ++h) {
    const float x = hs_s[h];
    kk = fmaf(x, Wk[l * 64 + h], kk);
    vv = fmaf(x, Wv[l * 64 + h], vv);
    qq = fmaf(x, Wq[l * 64 + h], qq);
  }
  // F.normalize(k): k / max(||k||, 1e-12)
  float nrm = sqrtf(wave_sum64(kk * kk));
  nrm = fmaxf(nrm, 1e-12f);
  k_tab[tok * 64 + l] = kk / nrm;
  v_tab[tok * 64 + l] = vv;
  q_tab[tok * 64 + l] = qq;
}

// ---------------------------------------------------------------------------
// Kernel B: per-batch backward scan + head.  One block (1 wave) per batch.
// Lane l owns component l of every H-vector.
// ---------------------------------------------------------------------------
__global__ __launch_bounds__(64) void scan_head(
    const int* __restrict__ seq, const float* __restrict__ k_tab,
    const float* __restrict__ v_tab, const float* __restrict__ q_tab,
    const float* __restrict__ Wrp, const float* __restrict__ brp,
    const float* __restrict__ Wout, const float* __restrict__ bout,
    float* __restrict__ out) {
  __shared__ float k_s[4096];
  __shared__ float v_s[4096];
  __shared__ int tok_s[2048];
  __shared__ float tmp[64];
  const int b = blockIdx.x;
  const int l = threadIdx.x;

  // Stage tables + this batch's token row into LDS (vectorized).
#pragma unroll
  for (int i = 0; i < 16; ++i) {
    ((float4*)k_s)[l + 64 * i] = ((const float4*)k_tab)[l + 64 * i];
    ((float4*)v_s)[l + 64 * i] = ((const float4*)v_tab)[l + 64 * i];
  }
  const int4* seq4 = (const int4*)(seq + b * 2048);
#pragma unroll
  for (int i = 0; i < 8; ++i) ((int4*)tok_s)[l + 64 * i] = seq4[l + 64 * i];
  __syncthreads();

  float u = q_tab[tok_s[2047] * 64 + l];  // u = q
  float r = 0.f;

  // Backward scan over t = 2046..0, software-pipelined in bodies of 8:
  //   - kv for body i loaded during body i-1 (addresses from tokens loaded
  //     during body i-2), so the 2-level LDS chains stay off the FP chain.
  constexpr int U = 8;
  constexpr int NB = 255;  // 255*8 = 2040 steps; tail of 7
  float ka[U], va[U];
  int tkn[U];
#pragma unroll
  for (int j = 0; j < U; ++j) {  // kv for body 0
    const int tk = tok_s[2046 - j];
    ka[j] = k_s[tk * 64 + l];
    va[j] = v_s[tk * 64 + l];
  }
#pragma unroll
  for (int j = 0; j < U; ++j) tkn[j] = tok_s[2046 - U - j];  // tokens for body 1

  int t = 2046;
  for (int body = 0; body < NB; ++body) {
    float kb[U], vb[U];
    int tk2[U];
    // Prefetch kv for body+1 (tokens already in regs -> no wait on chain).
#pragma unroll
    for (int j = 0; j < U; ++j) {
      kb[j] = k_s[tkn[j] * 64 + l];
      vb[j] = v_s[tkn[j] * 64 + l];
    }
    // Prefetch tokens for body+2 (clamped; clamped reads are never consumed).
    const int tb2 = t - 2 * U;
#pragma unroll
    for (int j = 0; j < U; ++j) {
      const int idx = tb2 - j;
      tk2[j] = tok_s[idx < 0 ? 0 : idx];
    }
    // 8 dependent scan steps.
#pragma unroll
    for (int j = 0; j < U; ++j) {
      const float s = wave_sum64(ka[j] * u);
      u = fmaf(-s, ka[j], u);
      r = fmaf(s, va[j], r);
    }
#pragma unroll
    for (int j = 0; j < U; ++j) {
      ka[j] = kb[j];
      va[j] = vb[j];
      tkn[j] = tk2[j];
    }
    t -= U;
  }
  // Tail: t == 6; ka/va hold steps 6..0 in j=0..6.
#pragma unroll
  for (int j = 0; j < 7; ++j) {
    const float s = wave_sum64(ka[j] * u);
    u = fmaf(-s, ka[j], u);
    r = fmaf(s, va[j], r);
  }

  // Head: r -> Wrp -> Wout
  tmp[l] = r;
  __syncthreads();
  float acc = brp[l];
#pragma unroll
  for (int j = 0; j < 64; ++j) acc = fmaf(tmp[j], Wrp[l * 64 + j], acc);
  __syncthreads();
  tmp[l] = acc;
  __syncthreads();
  float o = bout[l];
#pragma unroll
  for (int i = 0; i < 64; ++i) o = fmaf(tmp[i], Wout[l * 64 + i], o);
  out[b * 64 + l] = o;
}

extern "C" void kernel_launch(void* const* d_in, const int* in_sizes, int n_in,
                              void* d_out, int out_size, void* d_ws,
                              size_t ws_size, hipStream_t stream) {
  const int* seq = (const int*)d_in[0];
  const float* embed = (const float*)d_in[1];
  const float* W1 = (const float*)d_in[2];
  const float* b1 = (const float*)d_in[3];
  const float* W2 = (const float*)d_in[4];
  const float* b2 = (const float*)d_in[5];
  const float* gamma = (const float*)d_in[6];
  const float* beta = (const float*)d_in[7];
  const float* Wk = (const float*)d_in[8];
  const float* Wv = (const float*)d_in[9];
  const float* Wq = (const float*)d_in[10];
  const float* Wrp = (const float*)d_in[11];
  const float* brp = (const float*)d_in[12];
  const float* Wout = (const float*)d_in[13];
  const float* bout = (const float*)d_in[14];

  float* wsf = (float*)d_ws;
  float* k_tab = wsf;          // 4096 floats
  float* v_tab = wsf + 4096;   // 4096 floats
  float* q_tab = wsf + 8192;   // 4096 floats

  build_tables<<<64, 64, 0, stream>>>(embed, W1, b1, W2, b2, gamma, beta, Wk,
                                      Wv, Wq, k_tab, v_tab, q_tab);
  scan_head<<<256, 64, 0, stream>>>(seq, k_tab, v_tab, q_tab, Wrp, brp, Wout,
                                    bout, (float*)d_out);
}

// Round 2
// 156.001 us; speedup vs baseline: 1.2799x; 1.2799x over previous
//
#include <hip/hip_runtime.h>

// ---------------------------------------------------------------------------
// DeltaModel: B=256, L=2048, H=V=64.
// Identities:
//  (1) hs/k/v/q depend only on token id (V=64) -> 64-entry tables.
//  (2) r = M_N q, M linear recurrence -> backward scan. With y_a = k_a . u
//      maintained for ALL 64 token keys (lane a holds y_a):
//        s = y[b_t];  y_a -= s * G[a][b_t];  r += s * v[b_t]
//      where G[a][b] = k_a . k_b (Gram table). Critical path per step is
//      readlane -> fmaf (~10 cyc) instead of a full 64-lane reduction.
// ---------------------------------------------------------------------------

#define DPP_ADD_F32(x, ctrl, rm, bm, bc)                                      \
  (x) = (x) + __int_as_float(__builtin_amdgcn_update_dpp(                     \
            0, __float_as_int(x), (ctrl), (rm), (bm), (bc)))

__device__ __forceinline__ float wave_sum64(float x) {
  DPP_ADD_F32(x, 0x111, 0xf, 0xf, true);   // row_shr:1
  DPP_ADD_F32(x, 0x112, 0xf, 0xf, true);   // row_shr:2
  DPP_ADD_F32(x, 0x114, 0xf, 0xf, true);   // row_shr:4
  DPP_ADD_F32(x, 0x118, 0xf, 0xf, true);   // row_shr:8
  DPP_ADD_F32(x, 0x142, 0xa, 0xf, false);  // row_bcast:15
  DPP_ADD_F32(x, 0x143, 0xc, 0xf, false);  // row_bcast:31 -> lane 63 total
  return __int_as_float(__builtin_amdgcn_readlane(__float_as_int(x), 63));
}

__device__ __forceinline__ float readlane_f(float x, int lane) {
  return __int_as_float(__builtin_amdgcn_readlane(__float_as_int(x), lane));
}

// ---------------------------------------------------------------------------
// Kernel A: per-token tables k_n, v, q. Weights staged in padded LDS so both
// the global reads (coalesced) and LDS reads (2-way, free) are fast.
// ---------------------------------------------------------------------------
__global__ __launch_bounds__(64) void build_tables(
    const float* __restrict__ embed, const float* __restrict__ W1,
    const float* __restrict__ b1, const float* __restrict__ W2,
    const float* __restrict__ b2, const float* __restrict__ gamma,
    const float* __restrict__ beta, const float* __restrict__ Wk,
    const float* __restrict__ Wv, const float* __restrict__ Wq,
    float* __restrict__ k_tab, float* __restrict__ v_tab,
    float* __restrict__ q_tab) {
  __shared__ float Wbuf[8448];  // reused: W1(128x65) / W2(64x131) / Wk+Wv / Wq
  __shared__ float e_s[64];
  __shared__ float f1_s[128];
  __shared__ float hs_s[64];
  const int tok = blockIdx.x;
  const int l = threadIdx.x;

  const float e = embed[tok * 64 + l];
  e_s[l] = e;
  for (int i = 0; i < 128; ++i) Wbuf[i * 65 + l] = W1[i * 64 + l];
  __syncthreads();

  float a0 = b1[l], a1 = b1[l + 64];
#pragma unroll
  for (int h = 0; h < 64; ++h) {
    a0 = fmaf(e_s[h], Wbuf[l * 65 + h], a0);
    a1 = fmaf(e_s[h], Wbuf[(l + 64) * 65 + h], a1);
  }
  f1_s[l] = fmaxf(a0, 0.f);
  f1_s[l + 64] = fmaxf(a1, 0.f);
  __syncthreads();

  for (int i = 0; i < 128; ++i)
    Wbuf[(i >> 1) * 131 + (i & 1) * 64 + l] = W2[i * 64 + l];
  __syncthreads();

  float acc = b2[l];
#pragma unroll
  for (int j = 0; j < 128; ++j) acc = fmaf(f1_s[j], Wbuf[l * 131 + j], acc);
  const float hval = e + acc;

  const float mu = wave_sum64(hval) * (1.f / 64.f);
  const float d = hval - mu;
  const float var = wave_sum64(d * d) * (1.f / 64.f);
  const float hs = d * (1.f / sqrtf(var + 1e-5f)) * gamma[l] + beta[l];
  hs_s[l] = hs;
  __syncthreads();

  for (int i = 0; i < 64; ++i) {
    Wbuf[i * 65 + l] = Wk[i * 64 + l];
    Wbuf[4224 + i * 65 + l] = Wv[i * 64 + l];
  }
  __syncthreads();
  float kk = 0.f, vv = 0.f;
#pragma unroll
  for (int h = 0; h < 64; ++h) {
    kk = fmaf(hs_s[h], Wbuf[l * 65 + h], kk);
    vv = fmaf(hs_s[h], Wbuf[4224 + l * 65 + h], vv);
  }
  __syncthreads();
  for (int i = 0; i < 64; ++i) Wbuf[i * 65 + l] = Wq[i * 64 + l];
  __syncthreads();
  float qq = 0.f;
#pragma unroll
  for (int h = 0; h < 64; ++h) qq = fmaf(hs_s[h], Wbuf[l * 65 + h], qq);

  float nrm = fmaxf(sqrtf(wave_sum64(kk * kk)), 1e-12f);
  k_tab[tok * 64 + l] = kk / nrm;
  v_tab[tok * 64 + l] = vv;
  q_tab[tok * 64 + l] = qq;
}

// ---------------------------------------------------------------------------
// Kernel B: Gram tables. G[a][b] = k_a.k_b ; KQ[a][b] = q_a.k_b.
// ---------------------------------------------------------------------------
__global__ __launch_bounds__(64) void build_gram(
    const float* __restrict__ k_tab, const float* __restrict__ q_tab,
    float* __restrict__ G, float* __restrict__ KQ) {
  __shared__ float k_s[4160];  // 64 rows, padded 65
  __shared__ float q_s[64];
  const int a = blockIdx.x;
  const int l = threadIdx.x;
  for (int i = 0; i < 64; ++i) k_s[i * 65 + l] = k_tab[i * 64 + l];
  q_s[l] = q_tab[a * 64 + l];
  __syncthreads();
  float g = 0.f, kq = 0.f;
#pragma unroll
  for (int h = 0; h < 64; ++h) {
    g = fmaf(k_s[a * 65 + h], k_s[l * 65 + h], g);
    kq = fmaf(q_s[h], k_s[l * 65 + h], kq);
  }
  G[a * 64 + l] = g;
  KQ[a * 64 + l] = kq;
}

// ---------------------------------------------------------------------------
// Kernel C: per-batch scan + head. One wave per batch. Lane a owns y_a.
// Per step: s = readlane(y, b); y -= s*Gcol; r += s*vcol, with Gcol/vcol
// prefetched 64 steps ahead from the token stream (known in advance).
// Slot 0 is a dummy (token 64 -> zeroed row) padding 2047 -> 2048 steps.
// ---------------------------------------------------------------------------
__global__ __launch_bounds__(64) void scan_head(
    const int* __restrict__ seq, const float* __restrict__ Gg,
    const float* __restrict__ KQ, const float* __restrict__ v_tab,
    const float* __restrict__ Wrp, const float* __restrict__ brp,
    const float* __restrict__ Wout, const float* __restrict__ bout,
    float* __restrict__ out) {
  __shared__ float G_s[4160];  // 65 rows of 64 (row 64 = zeros)
  __shared__ float v_s[4160];
  __shared__ float tmp[64];
  const int b = blockIdx.x;
  const int l = threadIdx.x;

#pragma unroll
  for (int i = 0; i < 16; ++i) {
    ((float4*)G_s)[l + 64 * i] = ((const float4*)Gg)[l + 64 * i];
    ((float4*)v_s)[l + 64 * i] = ((const float4*)v_tab)[l + 64 * i];
  }
  G_s[4096 + l] = 0.f;
  v_s[4096 + l] = 0.f;

  const int* tokp = seq + b * 2048;
  int tok_cur = tokp[2047 - l];        // block 0: slot m = lane, t = 2047-m
  int tok_nxt = tokp[2047 - 64 - l];   // block 1
  __syncthreads();

  const int qt = __builtin_amdgcn_readlane(tok_cur, 0);  // t=2047 token -> q
  float y = KQ[qt * 64 + l];                             // y_a = k_a . q
  float r = 0.f;
  if (l == 0) tok_cur = 64;  // slot 0 is the dummy step

  float gcol[64], vcol[64];
#pragma unroll
  for (int j = 0; j < 64; ++j) {
    const int bj = __builtin_amdgcn_readlane(tok_cur, j);
    gcol[j] = G_s[bj * 64 + l];
    vcol[j] = v_s[bj * 64 + l];
  }

  for (int n = 0; n < 32; ++n) {
    const int tok_fut = (n <= 29) ? tokp[2047 - 64 * (n + 2) - l] : 0;
#pragma unroll
    for (int j = 0; j < 64; ++j) {
      // prefetch for block n+1 (overwrites slot j after its use below)
      const int bn = __builtin_amdgcn_readlane(tok_nxt, j);
      const float gnew = G_s[bn * 64 + l];
      const float vnew = v_s[bn * 64 + l];
      // step m = 64n + j
      const int bc = __builtin_amdgcn_readlane(tok_cur, j) & 63;
      const float s = readlane_f(y, bc);
      y = fmaf(-s, gcol[j], y);
      r = fmaf(s, vcol[j], r);
      gcol[j] = gnew;
      vcol[j] = vnew;
    }
    tok_cur = tok_nxt;
    tok_nxt = tok_fut;
  }

  // Head: r -> Wrp -> Wout (weights re-staged padded into G_s / v_s)
  tmp[l] = r;
  for (int i = 0; i < 64; ++i) {
    G_s[i * 65 + l] = Wrp[i * 64 + l];
    v_s[i * 65 + l] = Wout[i * 64 + l];
  }
  __syncthreads();
  float acc = brp[l];
#pragma unroll
  for (int j = 0; j < 64; ++j) acc = fmaf(tmp[j], G_s[l * 65 + j], acc);
  __syncthreads();
  tmp[l] = acc;
  __syncthreads();
  float o = bout[l];
#pragma unroll
  for (int i = 0; i < 64; ++i) o = fmaf(tmp[i], v_s[l * 65 + i], o);
  out[b * 64 + l] = o;
}

extern "C" void kernel_launch(void* const* d_in, const int* in_sizes, int n_in,
                              void* d_out, int out_size, void* d_ws,
                              size_t ws_size, hipStream_t stream) {
  const int* seq = (const int*)d_in[0];
  const float* embed = (const float*)d_in[1];
  const float* W1 = (const float*)d_in[2];
  const float* b1 = (const float*)d_in[3];
  const float* W2 = (const float*)d_in[4];
  const float* b2 = (const float*)d_in[5];
  const float* gamma = (const float*)d_in[6];
  const float* beta = (const float*)d_in[7];
  const float* Wk = (const float*)d_in[8];
  const float* Wv = (const float*)d_in[9];
  const float* Wq = (const float*)d_in[10];
  const float* Wrp = (const float*)d_in[11];
  const float* brp = (const float*)d_in[12];
  const float* Wout = (const float*)d_in[13];
  const float* bout = (const float*)d_in[14];

  float* wsf = (float*)d_ws;
  float* k_tab = wsf;           // 4096
  float* v_tab = wsf + 4096;    // 4096
  float* q_tab = wsf + 8192;    // 4096
  float* G = wsf + 12288;       // 4096
  float* KQ = wsf + 16384;      // 4096

  build_tables<<<64, 64, 0, stream>>>(embed, W1, b1, W2, b2, gamma, beta, Wk,
                                      Wv, Wq, k_tab, v_tab, q_tab);
  build_gram<<<64, 64, 0, stream>>>(k_tab, q_tab, G, KQ);
  scan_head<<<256, 64, 0, stream>>>(seq, G, KQ, v_tab, Wrp, brp, Wout, bout,
                                    (float*)d_out);
}

// Round 3
// 133.541 us; speedup vs baseline: 1.4951x; 1.1682x over previous
//
#include <hip/hip_runtime.h>

// ---------------------------------------------------------------------------
// DeltaModel: B=256, L=2048, H=V=64.
//  (1) hs/k/v/q depend only on token id (V=64) -> 64-entry tables.
//  (2) r = M_N q -> backward scan with y_a = k_a . u for all 64 keys:
//        s = y[b_t];  y -= s * G[.][b_t];  r += s * v[b_t]
//      G[a][b] = k_a.k_b. Critical path = readlane -> fma (~10 cyc/step).
//  (3) G,v packed as float2 -> one ds_read_b64 per step; double-buffered
//      64-deep register arrays so LDS latency is off the dependence chain.
// ---------------------------------------------------------------------------

#define DPP_ADD_F32(x, ctrl, rm, bm, bc)                                      \
  (x) = (x) + __int_as_float(__builtin_amdgcn_update_dpp(                     \
            0, __float_as_int(x), (ctrl), (rm), (bm), (bc)))

__device__ __forceinline__ float wave_sum64(float x) {
  DPP_ADD_F32(x, 0x111, 0xf, 0xf, true);   // row_shr:1
  DPP_ADD_F32(x, 0x112, 0xf, 0xf, true);   // row_shr:2
  DPP_ADD_F32(x, 0x114, 0xf, 0xf, true);   // row_shr:4
  DPP_ADD_F32(x, 0x118, 0xf, 0xf, true);   // row_shr:8
  DPP_ADD_F32(x, 0x142, 0xa, 0xf, false);  // row_bcast:15
  DPP_ADD_F32(x, 0x143, 0xc, 0xf, false);  // row_bcast:31 -> lane 63 total
  return __int_as_float(__builtin_amdgcn_readlane(__float_as_int(x), 63));
}

__device__ __forceinline__ float readlane_f(float x, int lane) {
  return __int_as_float(__builtin_amdgcn_readlane(__float_as_int(x), lane));
}

// ---------------------------------------------------------------------------
// Kernel A: per-token tables k_n, v, q (weights staged in padded LDS).
// ---------------------------------------------------------------------------
__global__ __launch_bounds__(64) void build_tables(
    const float* __restrict__ embed, const float* __restrict__ W1,
    const float* __restrict__ b1, const float* __restrict__ W2,
    const float* __restrict__ b2, const float* __restrict__ gamma,
    const float* __restrict__ beta, const float* __restrict__ Wk,
    const float* __restrict__ Wv, const float* __restrict__ Wq,
    float* __restrict__ k_tab, float* __restrict__ v_tab,
    float* __restrict__ q_tab) {
  __shared__ float Wbuf[8448];
  __shared__ float e_s[64];
  __shared__ float f1_s[128];
  __shared__ float hs_s[64];
  const int tok = blockIdx.x;
  const int l = threadIdx.x;

  const float e = embed[tok * 64 + l];
  e_s[l] = e;
  for (int i = 0; i < 128; ++i) Wbuf[i * 65 + l] = W1[i * 64 + l];
  __syncthreads();

  float a0 = b1[l], a1 = b1[l + 64];
#pragma unroll
  for (int h = 0; h < 64; ++h) {
    a0 = fmaf(e_s[h], Wbuf[l * 65 + h], a0);
    a1 = fmaf(e_s[h], Wbuf[(l + 64) * 65 + h], a1);
  }
  f1_s[l] = fmaxf(a0, 0.f);
  f1_s[l + 64] = fmaxf(a1, 0.f);
  __syncthreads();

  for (int i = 0; i < 128; ++i)
    Wbuf[(i >> 1) * 131 + (i & 1) * 64 + l] = W2[i * 64 + l];
  __syncthreads();

  float acc = b2[l];
#pragma unroll
  for (int j = 0; j < 128; ++j) acc = fmaf(f1_s[j], Wbuf[l * 131 + j], acc);
  const float hval = e + acc;

  const float mu = wave_sum64(hval) * (1.f / 64.f);
  const float d = hval - mu;
  const float var = wave_sum64(d * d) * (1.f / 64.f);
  const float hs = d * (1.f / sqrtf(var + 1e-5f)) * gamma[l] + beta[l];
  hs_s[l] = hs;
  __syncthreads();

  for (int i = 0; i < 64; ++i) {
    Wbuf[i * 65 + l] = Wk[i * 64 + l];
    Wbuf[4224 + i * 65 + l] = Wv[i * 64 + l];
  }
  __syncthreads();
  float kk = 0.f, vv = 0.f;
#pragma unroll
  for (int h = 0; h < 64; ++h) {
    kk = fmaf(hs_s[h], Wbuf[l * 65 + h], kk);
    vv = fmaf(hs_s[h], Wbuf[4224 + l * 65 + h], vv);
  }
  __syncthreads();
  for (int i = 0; i < 64; ++i) Wbuf[i * 65 + l] = Wq[i * 64 + l];
  __syncthreads();
  float qq = 0.f;
#pragma unroll
  for (int h = 0; h < 64; ++h) qq = fmaf(hs_s[h], Wbuf[l * 65 + h], qq);

  float nrm = fmaxf(sqrtf(wave_sum64(kk * kk)), 1e-12f);
  k_tab[tok * 64 + l] = kk / nrm;
  v_tab[tok * 64 + l] = vv;
  q_tab[tok * 64 + l] = qq;
}

// ---------------------------------------------------------------------------
// Kernel B: GV[a][l] = {G[a][l], v[a][l]} packed float2; KQ[a][l] = q_a.k_l.
// ---------------------------------------------------------------------------
__global__ __launch_bounds__(64) void build_gram(
    const float* __restrict__ k_tab, const float* __restrict__ q_tab,
    const float* __restrict__ v_tab, float2* __restrict__ GV,
    float* __restrict__ KQ) {
  __shared__ float k_s[4160];
  __shared__ float q_s[64];
  const int a = blockIdx.x;
  const int l = threadIdx.x;
  for (int i = 0; i < 64; ++i) k_s[i * 65 + l] = k_tab[i * 64 + l];
  q_s[l] = q_tab[a * 64 + l];
  __syncthreads();
  float g = 0.f, kq = 0.f;
#pragma unroll
  for (int h = 0; h < 64; ++h) {
    g = fmaf(k_s[a * 65 + h], k_s[l * 65 + h], g);
    kq = fmaf(q_s[h], k_s[l * 65 + h], kq);
  }
  GV[a * 64 + l] = make_float2(g, v_tab[a * 64 + l]);
  KQ[a * 64 + l] = kq;
}

// ---------------------------------------------------------------------------
// Kernel C: per-batch scan + head. One wave per batch. Lane a owns y_a.
// Double-buffered 64-step bodies: body consumes buffer X while issuing the
// ds_read_b64 prefetch for the next 64 steps into buffer Y -> LDS latency
// never sits on the readlane->fma dependence chain.
// ---------------------------------------------------------------------------
__global__ __launch_bounds__(64, 1) void scan_head(
    const int* __restrict__ seq, const float2* __restrict__ GVg,
    const float* __restrict__ KQ, const float* __restrict__ Wrp,
    const float* __restrict__ brp, const float* __restrict__ Wout,
    const float* __restrict__ bout, float* __restrict__ out) {
  __shared__ float2 GV_s[4160];  // 65 rows of 64 (row 64 = zeros, dummy tok)
  __shared__ float tmp[64];
  const int b = blockIdx.x;
  const int l = threadIdx.x;

#pragma unroll
  for (int i = 0; i < 32; ++i)
    ((float4*)GV_s)[l + 64 * i] = ((const float4*)GVg)[l + 64 * i];
  GV_s[4096 + l] = make_float2(0.f, 0.f);

  const int* tokp = seq + b * 2048;
  int tok_cur = tokp[2047 - l];       // block 0: slot j = lane, t = 2047-j
  int tok_nxt = tokp[2047 - 64 - l];  // block 1
  __syncthreads();

  const int qt = __builtin_amdgcn_readlane(tok_cur, 0);  // t=2047 token -> q
  float y = KQ[qt * 64 + l];                             // y_a = k_a . q
  float r = 0.f;
  if (l == 0) tok_cur = 64;  // slot 0 = dummy step (zero row)

  float2 gA[64], gB[64];
#pragma unroll
  for (int j = 0; j < 64; ++j) {
    const int bj = __builtin_amdgcn_readlane(tok_cur, j);
    gA[j] = GV_s[bj * 64 + l];
  }

  for (int n = 0; n < 16; ++n) {
    const int i2 = 2 * n + 2, i3 = 2 * n + 3;
    int tok_f1 = (i2 <= 31) ? tokp[2047 - 64 * i2 - l] : 0;
    // even body: consume A (block 2n), load B (block 2n+1)
#pragma unroll
    for (int j = 0; j < 64; ++j) {
      const int bn = __builtin_amdgcn_readlane(tok_nxt, j);
      const float2 gv = GV_s[bn * 64 + l];
      const int bc = __builtin_amdgcn_readlane(tok_cur, j) & 63;
      const float s = readlane_f(y, bc);
      y = fmaf(-s, gA[j].x, y);
      r = fmaf(s, gA[j].y, r);
      gB[j] = gv;
    }
    tok_cur = tok_nxt;
    tok_nxt = tok_f1;
    int tok_f2 = (i3 <= 31) ? tokp[2047 - 64 * i3 - l] : 0;
    // odd body: consume B (block 2n+1), load A (block 2n+2)
#pragma unroll
    for (int j = 0; j < 64; ++j) {
      const int bn = __builtin_amdgcn_readlane(tok_nxt, j);
      const float2 gv = GV_s[bn * 64 + l];
      const int bc = __builtin_amdgcn_readlane(tok_cur, j) & 63;
      const float s = readlane_f(y, bc);
      y = fmaf(-s, gB[j].x, y);
      r = fmaf(s, gB[j].y, r);
      gA[j] = gv;
    }
    tok_cur = tok_nxt;
    tok_nxt = tok_f2;
  }

  // Head: r -> Wrp -> Wout (weights staged padded into GV_s memory)
  float* Wb = (float*)GV_s;
  tmp[l] = r;
  for (int i = 0; i < 64; ++i) {
    Wb[i * 65 + l] = Wrp[i * 64 + l];
    Wb[4160 + i * 65 + l] = Wout[i * 64 + l];
  }
  __syncthreads();
  float acc = brp[l];
#pragma unroll
  for (int j = 0; j < 64; ++j) acc = fmaf(tmp[j], Wb[l * 65 + j], acc);
  __syncthreads();
  tmp[l] = acc;
  __syncthreads();
  float o = bout[l];
#pragma unroll
  for (int i = 0; i < 64; ++i) o = fmaf(tmp[i], Wb[4160 + l * 65 + i], o);
  out[b * 64 + l] = o;
}

extern "C" void kernel_launch(void* const* d_in, const int* in_sizes, int n_in,
                              void* d_out, int out_size, void* d_ws,
                              size_t ws_size, hipStream_t stream) {
  const int* seq = (const int*)d_in[0];
  const float* embed = (const float*)d_in[1];
  const float* W1 = (const float*)d_in[2];
  const float* b1 = (const float*)d_in[3];
  const float* W2 = (const float*)d_in[4];
  const float* b2 = (const float*)d_in[5];
  const float* gamma = (const float*)d_in[6];
  const float* beta = (const float*)d_in[7];
  const float* Wk = (const float*)d_in[8];
  const float* Wv = (const float*)d_in[9];
  const float* Wq = (const float*)d_in[10];
  const float* Wrp = (const float*)d_in[11];
  const float* brp = (const float*)d_in[12];
  const float* Wout = (const float*)d_in[13];
  const float* bout = (const float*)d_in[14];

  float* wsf = (float*)d_ws;
  float* k_tab = wsf;            // 4096
  float* v_tab = wsf + 4096;     // 4096
  float* q_tab = wsf + 8192;     // 4096
  float2* GV = (float2*)(wsf + 12288);  // 4096 float2 = 8192 floats
  float* KQ = wsf + 20480;       // 4096

  build_tables<<<64, 64, 0, stream>>>(embed, W1, b1, W2, b2, gamma, beta, Wk,
                                      Wv, Wq, k_tab, v_tab, q_tab);
  build_gram<<<64, 64, 0, stream>>>(k_tab, q_tab, v_tab, GV, KQ);
  scan_head<<<256, 64, 0, stream>>>(seq, GV, KQ, Wrp, brp, Wout, bout,
                                    (float*)d_out);
}